// Round 7
// baseline (56.134 us; speedup 1.0000x reference)
//
#include <hip/hip_runtime.h>
#include <hip/hip_bf16.h>

#define TSEQ   4096
#define NB     4
#define EMB    512
#define HS     32
#define NQ     16384      // NB * TSEQ

typedef float  f32x4  __attribute__((ext_vector_type(4)));
typedef __bf16 bf16x8 __attribute__((ext_vector_type(8)));
typedef __bf16 bf16x4 __attribute__((ext_vector_type(4)));

// ---------------------------------------------------------------------------
// Kernel 0: pack weights.
// blocks 0..95:  wt[96][512] bf16 = concat(Wq*s, Wk, Wv)^T (+ bsc biases)
// blocks 96..127: wpt[512][32] bf16 = Wp^T (for output-proj B-fragments)
// ---------------------------------------------------------------------------
__global__ __launch_bounds__(128) void wt_pack(
    const float* __restrict__ Wq, const float* __restrict__ bq,
    const float* __restrict__ Wk, const float* __restrict__ bk,
    const float* __restrict__ Wv, const float* __restrict__ bv,
    const float* __restrict__ Wp,
    __bf16* __restrict__ wt, float* __restrict__ bsc,
    __bf16* __restrict__ wpt)
{
    if (blockIdx.x < 96) {
        const int c  = blockIdx.x;        // 0..95 (concat col)
        const int m  = c >> 5;
        const int cc = c & 31;
        const float* W    = (m == 0) ? Wq : (m == 1) ? Wk : Wv;
        const float* bias = (m == 0) ? bq : (m == 1) ? bk : bv;
        const float s     = (m == 0) ? 0.17677669529663687f : 1.0f;

        const int d0 = threadIdx.x * 4;
        bf16x4 o = { (__bf16)(W[(size_t)(d0 + 0) * HS + cc] * s),
                     (__bf16)(W[(size_t)(d0 + 1) * HS + cc] * s),
                     (__bf16)(W[(size_t)(d0 + 2) * HS + cc] * s),
                     (__bf16)(W[(size_t)(d0 + 3) * HS + cc] * s) };
        *(bf16x4*)(wt + (size_t)c * EMB + d0) = o;
        if (threadIdx.x == 0) bsc[c] = bias[cc] * s;
    } else {
        const int col = (blockIdx.x - 96) * 16 + (threadIdx.x >> 3); // 0..511
        const int d0  = (threadIdx.x & 7) * 4;
        bf16x4 o = { (__bf16)Wp[(size_t)(d0 + 0) * EMB + col],
                     (__bf16)Wp[(size_t)(d0 + 1) * EMB + col],
                     (__bf16)Wp[(size_t)(d0 + 2) * EMB + col],
                     (__bf16)Wp[(size_t)(d0 + 3) * EMB + col] };
        *(bf16x4*)(wpt + (size_t)col * HS + d0) = o;
    }
}

// ---------------------------------------------------------------------------
// Kernel 1: MFMA QKV projection, split-K x4.  grid(1024), block 256 = 4 waves.
// (unchanged from R4/R6)
// ---------------------------------------------------------------------------
__global__ __launch_bounds__(256) void qkv_mfma(
    const float* __restrict__ x,
    const __bf16* __restrict__ wt, const float* __restrict__ bsc,
    __bf16* __restrict__ qbf, __bf16* __restrict__ kbf, __bf16* __restrict__ vtb)
{
    const int tid  = threadIdx.x;
    const int lane = tid & 63;
    const int w    = tid >> 6;        // 0..3 (K-quarter)
    const int lr = lane & 15;
    const int lh = lane >> 4;
    const int tok0 = blockIdx.x * 16;
    const int k0   = w * 128;

    const float*  xp = x + (size_t)(tok0 + lr) * EMB + k0 + lh * 8;
    const __bf16* wp = wt + (size_t)lr * EMB + k0 + lh * 8;   // + f*16*EMB + kt

    const f32x4 z = {0.f, 0.f, 0.f, 0.f};
    f32x4 acc[6] = {z, z, z, z, z, z};   // aq0,aq1,ak0,ak1,av0,av1

    bf16x8 xf_c, wf_c[6], xf_n, wf_n[6];
    {
        const float4 a4 = *(const float4*)(xp);
        const float4 b4 = *(const float4*)(xp + 4);
        xf_c = bf16x8{ (__bf16)a4.x, (__bf16)a4.y, (__bf16)a4.z, (__bf16)a4.w,
                       (__bf16)b4.x, (__bf16)b4.y, (__bf16)b4.z, (__bf16)b4.w };
        #pragma unroll
        for (int f = 0; f < 6; ++f)
            wf_c[f] = *(const bf16x8*)(wp + (size_t)f * 16 * EMB);
    }

    #pragma unroll
    for (int kt = 0; kt < 128; kt += 32) {
        const int ktn = (kt + 32 < 128) ? (kt + 32) : kt;
        {
            const float4 a4 = *(const float4*)(xp + ktn);
            const float4 b4 = *(const float4*)(xp + ktn + 4);
            xf_n = bf16x8{ (__bf16)a4.x, (__bf16)a4.y, (__bf16)a4.z, (__bf16)a4.w,
                           (__bf16)b4.x, (__bf16)b4.y, (__bf16)b4.z, (__bf16)b4.w };
            #pragma unroll
            for (int f = 0; f < 6; ++f)
                wf_n[f] = *(const bf16x8*)(wp + (size_t)f * 16 * EMB + ktn);
        }

        acc[0] = __builtin_amdgcn_mfma_f32_16x16x32_bf16(wf_c[0], xf_c, acc[0], 0, 0, 0);
        acc[1] = __builtin_amdgcn_mfma_f32_16x16x32_bf16(wf_c[1], xf_c, acc[1], 0, 0, 0);
        acc[2] = __builtin_amdgcn_mfma_f32_16x16x32_bf16(wf_c[2], xf_c, acc[2], 0, 0, 0);
        acc[3] = __builtin_amdgcn_mfma_f32_16x16x32_bf16(wf_c[3], xf_c, acc[3], 0, 0, 0);
        acc[4] = __builtin_amdgcn_mfma_f32_16x16x32_bf16(xf_c, wf_c[4], acc[4], 0, 0, 0);
        acc[5] = __builtin_amdgcn_mfma_f32_16x16x32_bf16(xf_c, wf_c[5], acc[5], 0, 0, 0);

        xf_c = xf_n;
        #pragma unroll
        for (int f = 0; f < 6; ++f) wf_c[f] = wf_n[f];
    }

    __shared__ float red[3 * 6 * 256];
    if (w > 0) {
        #pragma unroll
        for (int i = 0; i < 6; ++i)
            *(f32x4*)&red[((w - 1) * 6 + i) * 256 + lane * 4] = acc[i];
    }
    __syncthreads();
    if (w != 0) return;

    #pragma unroll
    for (int i = 0; i < 6; ++i)
        #pragma unroll
        for (int ww = 0; ww < 3; ++ww)
            acc[i] += *(const f32x4*)&red[(ww * 6 + i) * 256 + lane * 4];

    #pragma unroll
    for (int f = 0; f < 2; ++f) {
        const int cb = f * 16 + lh * 4;
        const float4 bqv = *(const float4*)(bsc + cb);
        const float4 bkv = *(const float4*)(bsc + 32 + cb);
        bf16x4 oq = { (__bf16)(acc[f][0] + bqv.x), (__bf16)(acc[f][1] + bqv.y),
                      (__bf16)(acc[f][2] + bqv.z), (__bf16)(acc[f][3] + bqv.w) };
        bf16x4 ok = { (__bf16)(acc[2+f][0] + bkv.x), (__bf16)(acc[2+f][1] + bkv.y),
                      (__bf16)(acc[2+f][2] + bkv.z), (__bf16)(acc[2+f][3] + bkv.w) };
        *(bf16x4*)(qbf + (size_t)(tok0 + lr) * HS + cb) = oq;
        *(bf16x4*)(kbf + (size_t)(tok0 + lr) * HS + cb) = ok;
    }
    {
        const int b    = tok0 >> 12;
        const int t_in = (tok0 & (TSEQ - 1)) + lh * 4;
        #pragma unroll
        for (int f = 0; f < 2; ++f) {
            const int d = f * 16 + lr;
            const float bv1 = bsc[64 + d];
            bf16x4 o = { (__bf16)(acc[4+f][0] + bv1), (__bf16)(acc[4+f][1] + bv1),
                         (__bf16)(acc[4+f][2] + bv1), (__bf16)(acc[4+f][3] + bv1) };
            *(bf16x4*)(vtb + ((size_t)(b * HS + d)) * TSEQ + t_in) = o;
        }
    }
}

// ---------------------------------------------------------------------------
// Kernel 2: FUSED causal attention + output projection, SWAPPED-S edition.
// grid(128 strips, 4 batches), block 512 = 8 waves; wave w does key-tiles
// w, w+8, ... of the strip (32 q rows).  Swapped QK^T: S^T = mfma(K_A, Q_B)
// puts q=lane&15 (lane-local row) -> P packs to bf16x4 ds_write_b64 (4/tile
// vs 16 scalar b16), lp is a per-lane scalar, and PV A-frags come back as 2
// swizzled ds_read_b128 (2-way banks = free).  Then LDS o-reduce across the
// 8 waves, normalize, and project vs bf16 Wp^T.  No running max (|S| < ~2).
// LDS 67KB -> 2 blocks/CU = 4 waves/SIMD (R6 was 1 block/CU, 2 waves/SIMD).
// ---------------------------------------------------------------------------
__device__ __forceinline__ void s_stage2(
    const bf16x8 ck0, const bf16x8 ck1,
    const bf16x8 qb0, const bf16x8 qb1,
    int kt, int q0, int lr, int lh, int swz,
    float lp[2], char* Pb)
{
    const f32x4 z = {0.f, 0.f, 0.f, 0.f};
    // S^T[key][q]: A=K (row=key_l=lr, k=d), B=Q (col=q_l=lr, k=d)
    f32x4 st00 = __builtin_amdgcn_mfma_f32_16x16x32_bf16(ck0, qb0, z, 0, 0, 0);
    f32x4 st01 = __builtin_amdgcn_mfma_f32_16x16x32_bf16(ck1, qb0, z, 0, 0, 0);
    f32x4 st10 = __builtin_amdgcn_mfma_f32_16x16x32_bf16(ck0, qb1, z, 0, 0, 0);
    f32x4 st11 = __builtin_amdgcn_mfma_f32_16x16x32_bf16(ck1, qb1, z, 0, 0, 0);

    float P[2][2][4];   // [qh][kh][r]; key_l = kh*16+lh*4+r, q_l = qh*16+lr
    #pragma unroll
    for (int r = 0; r < 4; ++r) {
        P[0][0][r] = st00[r]; P[0][1][r] = st01[r];
        P[1][0][r] = st10[r]; P[1][1][r] = st11[r];
    }

    if (kt != q0) {                       // full tile (wave-uniform)
        #pragma unroll
        for (int qh = 0; qh < 2; ++qh)
            #pragma unroll
            for (int kh = 0; kh < 2; ++kh)
                #pragma unroll
                for (int r = 0; r < 4; ++r)
                    P[qh][kh][r] = __expf(P[qh][kh][r]);
    } else {                              // diagonal: key <= q mask
        #pragma unroll
        for (int qh = 0; qh < 2; ++qh)
            #pragma unroll
            for (int kh = 0; kh < 2; ++kh)
                #pragma unroll
                for (int r = 0; r < 4; ++r) {
                    const int key_l = kh * 16 + lh * 4 + r;
                    const int q_l   = qh * 16 + lr;
                    P[qh][kh][r] = (key_l <= q_l) ? __expf(P[qh][kh][r]) : 0.f;
                }
    }

    #pragma unroll
    for (int qh = 0; qh < 2; ++qh) {
        #pragma unroll
        for (int kh = 0; kh < 2; ++kh)
            #pragma unroll
            for (int r = 0; r < 4; ++r)
                lp[qh] += P[qh][kh][r];
    }

    // P^T[q][key] bf16, row stride 128B, 16B-chunk XOR swizzle by (q&7)
    #pragma unroll
    for (int qh = 0; qh < 2; ++qh)
        #pragma unroll
        for (int kh = 0; kh < 2; ++kh) {
            const int q    = qh * 16 + lr;
            const int byte = q * 128 + ((kh * 32 + lh * 8) ^ swz);
            bf16x4 pk = { (__bf16)P[qh][kh][0], (__bf16)P[qh][kh][1],
                          (__bf16)P[qh][kh][2], (__bf16)P[qh][kh][3] };
            *(bf16x4*)(Pb + byte) = pk;
        }
}

__device__ __forceinline__ void strip_proc2(
    int kt0, int kend, int q0,
    const bf16x8 qb0, const bf16x8 qb1,
    const __bf16* kbase, const __bf16* vbase,
    char* Pl,                         // 8KB: two 4KB buffers
    f32x4 o[4], float lp[2],
    int lr, int lh, int swz, int rdA, int rdB)
{
    if (kt0 >= kend) return;

    bf16x8 kf0 = *(const bf16x8*)(kbase + (size_t)kt0 * HS);
    bf16x8 kf1 = *(const bf16x8*)(kbase + (size_t)(kt0 + 16) * HS);
    bf16x8 vf0 = *(const bf16x8*)(vbase + kt0);
    bf16x8 vf1 = *(const bf16x8*)(vbase + kt0 + 16 * TSEQ);

    bf16x8 cv0p, cv1p;
    int pb = 1;
    {
        const bf16x8 ck0 = kf0, ck1 = kf1;
        cv0p = vf0; cv1p = vf1;
        const int ktn = (kt0 + 256 < kend) ? (kt0 + 256) : kt0;
        kf0 = *(const bf16x8*)(kbase + (size_t)ktn * HS);
        kf1 = *(const bf16x8*)(kbase + (size_t)(ktn + 16) * HS);
        vf0 = *(const bf16x8*)(vbase + ktn);
        vf1 = *(const bf16x8*)(vbase + ktn + 16 * TSEQ);
        s_stage2(ck0, ck1, qb0, qb1, kt0, q0, lr, lh, swz, lp, Pl);
    }

    for (int kt = kt0 + 256; kt < kend; kt += 256) {
        const bf16x8 ck0 = kf0, ck1 = kf1, cv0 = vf0, cv1 = vf1;
        const int ktn = (kt + 256 < kend) ? (kt + 256) : kt;
        kf0 = *(const bf16x8*)(kbase + (size_t)ktn * HS);
        kf1 = *(const bf16x8*)(kbase + (size_t)(ktn + 16) * HS);
        vf0 = *(const bf16x8*)(vbase + ktn);
        vf1 = *(const bf16x8*)(vbase + ktn + 16 * TSEQ);

        // read PREVIOUS tile's P A-frags first ...
        const char* pbase = Pl + (pb ^ 1) * 4096;
        const bf16x8 pa0 = *(const bf16x8*)(pbase + rdA);
        const bf16x8 pa1 = *(const bf16x8*)(pbase + rdB);

        // ... S-stage of current tile into buf pb ...
        s_stage2(ck0, ck1, qb0, qb1, kt, q0, lr, lh, swz, lp, Pl + pb * 4096);

        // ... PV of previous tile fills the RAW gap.
        o[0] = __builtin_amdgcn_mfma_f32_16x16x32_bf16(pa0, cv0p, o[0], 0, 0, 0);
        o[1] = __builtin_amdgcn_mfma_f32_16x16x32_bf16(pa0, cv1p, o[1], 0, 0, 0);
        o[2] = __builtin_amdgcn_mfma_f32_16x16x32_bf16(pa1, cv0p, o[2], 0, 0, 0);
        o[3] = __builtin_amdgcn_mfma_f32_16x16x32_bf16(pa1, cv1p, o[3], 0, 0, 0);

        cv0p = cv0; cv1p = cv1; pb ^= 1;
    }

    {
        const char* pbase = Pl + (pb ^ 1) * 4096;
        const bf16x8 pa0 = *(const bf16x8*)(pbase + rdA);
        const bf16x8 pa1 = *(const bf16x8*)(pbase + rdB);
        o[0] = __builtin_amdgcn_mfma_f32_16x16x32_bf16(pa0, cv0p, o[0], 0, 0, 0);
        o[1] = __builtin_amdgcn_mfma_f32_16x16x32_bf16(pa0, cv1p, o[1], 0, 0, 0);
        o[2] = __builtin_amdgcn_mfma_f32_16x16x32_bf16(pa1, cv0p, o[2], 0, 0, 0);
        o[3] = __builtin_amdgcn_mfma_f32_16x16x32_bf16(pa1, cv1p, o[3], 0, 0, 0);
    }
}

__global__ __launch_bounds__(512) void attn_fused(
    const __bf16* __restrict__ qbf, const __bf16* __restrict__ kbf,
    const __bf16* __restrict__ vtb,
    const __bf16* __restrict__ wpt, const float* __restrict__ bp,
    float* __restrict__ out)
{
    const int p   = blockIdx.x;       // strip: queries [p*32, p*32+32)
    const int b   = blockIdx.y;
    const int tid = threadIdx.x;
    const int w    = tid >> 6;        // 0..7
    const int lane = tid & 63;
    const int lr = lane & 15;
    const int lh = lane >> 4;

    const int q0   = p * 32;
    const int kend = q0 + 32;

    // LDS: [0,64K) union{ Pl[8 waves][2][4096B] | red[8][4][256] f32 (32K) }
    //      [64K,65K) lpred[8][32] f32 ; [65K,67K) attn_s[32][32] bf16
    extern __shared__ char smem[];
    char*   myPl   = smem + w * 8192;
    float*  red    = (float*)smem;
    float*  lpred  = (float*)(smem + 65536);
    __bf16* attn_s = (__bf16*)(smem + 65536 + 1024);

    // Q B-frags (col=q_l=lr, k=d)
    const __bf16* qp = qbf + ((size_t)(b * TSEQ + q0 + lr)) * HS + lh * 8;
    const bf16x8 qb0 = *(const bf16x8*)qp;
    const bf16x8 qb1 = *(const bf16x8*)(qp + 16 * HS);

    const __bf16* kbase = kbf + ((size_t)(b * TSEQ + lr)) * HS + lh * 8;
    const __bf16* vbase = vtb + (size_t)(b * HS + lr) * TSEQ + lh * 8;

    const int swz = (lr & 7) << 4;    // P^T chunk swizzle ((q&7)<<4; q&7==lr&7)
    const int rdA = lr * 128 + ((lh * 16) ^ swz);
    const int rdB = (16 + lr) * 128 + ((lh * 16) ^ swz);

    const f32x4 z = {0.f, 0.f, 0.f, 0.f};
    f32x4 o[4] = {z, z, z, z};        // [qh*2+dh]: row=q_l, col=d_l
    float lp[2] = {0.f, 0.f};

    strip_proc2(w * 32, kend, q0, qb0, qb1, kbase, vbase, myPl,
                o, lp, lr, lh, swz, rdA, rdB);

    // lp: lanes lh=0..3 share q=lr -> xor 16, 32
    lp[0] += __shfl_xor(lp[0], 16, 64);
    lp[0] += __shfl_xor(lp[0], 32, 64);
    lp[1] += __shfl_xor(lp[1], 16, 64);
    lp[1] += __shfl_xor(lp[1], 32, 64);

    __syncthreads();   // all PV reads done before red overwrites Pl

    #pragma unroll
    for (int f = 0; f < 4; ++f)
        *(f32x4*)&red[(w * 4 + f) * 256 + lane * 4] = o[f];
    if (lh == 0) {
        lpred[w * 32 + lr]      = lp[0];
        lpred[w * 32 + 16 + lr] = lp[1];
    }
    __syncthreads();

    // reduce: wave w<4 sums fragment f=w over the 8 waves, normalizes
    if (w < 4) {
        const int qh = w >> 1;
        const int dh = w & 1;
        f32x4 sum = z;
        #pragma unroll
        for (int ww = 0; ww < 8; ++ww)
            sum += *(const f32x4*)&red[(ww * 4 + w) * 256 + lane * 4];
        #pragma unroll
        for (int r = 0; r < 4; ++r) {
            const int q = qh * 16 + lh * 4 + r;
            float L = 0.f;
            #pragma unroll
            for (int ww = 0; ww < 8; ++ww)
                L += lpred[ww * 32 + q];
            attn_s[q * 32 + dh * 16 + lr] = (__bf16)(sum[r] / L);
        }
    }
    __syncthreads();

    // projection: wave w -> cols [w*64, w*64+64)
    {
        const bf16x8 a0 = *(const bf16x8*)(attn_s + lr * 32 + lh * 8);
        const bf16x8 a1 = *(const bf16x8*)(attn_s + (16 + lr) * 32 + lh * 8);
        const int c0 = w * 64;

        #pragma unroll
        for (int g = 0; g < 4; ++g) {
            const int c = c0 + g * 16;
            const bf16x8 wb = *(const bf16x8*)(wpt + (size_t)(c + lr) * HS + lh * 8);
            f32x4 d0 = __builtin_amdgcn_mfma_f32_16x16x32_bf16(a0, wb, z, 0, 0, 0);
            f32x4 d1 = __builtin_amdgcn_mfma_f32_16x16x32_bf16(a1, wb, z, 0, 0, 0);
            const float bpv = bp[c + lr];
            #pragma unroll
            for (int r = 0; r < 4; ++r) {
                const int row = lh * 4 + r;
                out[(size_t)(b * TSEQ + q0 + row)      * EMB + c + lr] = d0[r] + bpv;
                out[(size_t)(b * TSEQ + q0 + 16 + row) * EMB + c + lr] = d1[r] + bpv;
            }
        }
    }
}

// ---------------------------------------------------------------------------
extern "C" void kernel_launch(void* const* d_in, const int* in_sizes, int n_in,
                              void* d_out, int out_size, void* d_ws, size_t ws_size,
                              hipStream_t stream)
{
    const float* x  = (const float*)d_in[0];
    const float* Wq = (const float*)d_in[1];
    const float* bq = (const float*)d_in[2];
    const float* Wk = (const float*)d_in[3];
    const float* bk = (const float*)d_in[4];
    const float* Wv = (const float*)d_in[5];
    const float* bv = (const float*)d_in[6];
    const float* Wp = (const float*)d_in[7];
    const float* bp = (const float*)d_in[8];
    float* out = (float*)d_out;

    // workspace layout (bytes):
    //   wt  [96*512] bf16 @ 0        (96 KB)
    //   bsc [96] f32      @ 96 KB
    //   wpt [512*32] bf16 @ 128 KB   (32 KB)
    //   qbf [NQ*32] bf16  @ 1 MB
    //   kbf [NQ*32] bf16  @ 2 MB
    //   vtb [NB*32*TSEQ]  @ 3 MB     -> 4 MB total
    char* ws = (char*)d_ws;
    __bf16* wt  = (__bf16*)(ws);
    float*  bsc = (float*)(ws + 96 * 1024);
    __bf16* wpt = (__bf16*)(ws + 128 * 1024);
    __bf16* qbf = (__bf16*)(ws + (size_t)1 * 1024 * 1024);
    __bf16* kbf = (__bf16*)(ws + (size_t)2 * 1024 * 1024);
    __bf16* vtb = (__bf16*)(ws + (size_t)3 * 1024 * 1024);

    wt_pack<<<dim3(128), 128, 0, stream>>>(Wq, bq, Wk, bk, Wv, bv, Wp,
                                           wt, bsc, wpt);
    qkv_mfma<<<dim3(NQ / 16), 256, 0, stream>>>(x, wt, bsc, qbf, kbf, vtb);
    attn_fused<<<dim3(128, NB), 512, 68608, stream>>>(qbf, kbf, vtb, wpt, bp, out);
}

// Round 8
// 48.001 us; speedup vs baseline: 1.1694x; 1.1694x over previous
//
#include <hip/hip_runtime.h>
#include <hip/hip_bf16.h>

#define TSEQ   4096
#define NB     4
#define EMB    512
#define HS     32
#define NQ     16384      // NB * TSEQ

typedef float  f32x4  __attribute__((ext_vector_type(4)));
typedef __bf16 bf16x8 __attribute__((ext_vector_type(8)));
typedef __bf16 bf16x4 __attribute__((ext_vector_type(4)));

// ---------------------------------------------------------------------------
// Kernel 0: pack weights.  (unchanged from R6)
// blocks 0..95:  wt[96][512] bf16 = concat(Wq*s, Wk, Wv)^T (+ bsc biases)
// blocks 96..127: wpt[512][32] bf16 = Wp^T
// ---------------------------------------------------------------------------
__global__ __launch_bounds__(128) void wt_pack(
    const float* __restrict__ Wq, const float* __restrict__ bq,
    const float* __restrict__ Wk, const float* __restrict__ bk,
    const float* __restrict__ Wv, const float* __restrict__ bv,
    const float* __restrict__ Wp,
    __bf16* __restrict__ wt, float* __restrict__ bsc,
    __bf16* __restrict__ wpt)
{
    if (blockIdx.x < 96) {
        const int c  = blockIdx.x;
        const int m  = c >> 5;
        const int cc = c & 31;
        const float* W    = (m == 0) ? Wq : (m == 1) ? Wk : Wv;
        const float* bias = (m == 0) ? bq : (m == 1) ? bk : bv;
        const float s     = (m == 0) ? 0.17677669529663687f : 1.0f;

        const int d0 = threadIdx.x * 4;
        bf16x4 o = { (__bf16)(W[(size_t)(d0 + 0) * HS + cc] * s),
                     (__bf16)(W[(size_t)(d0 + 1) * HS + cc] * s),
                     (__bf16)(W[(size_t)(d0 + 2) * HS + cc] * s),
                     (__bf16)(W[(size_t)(d0 + 3) * HS + cc] * s) };
        *(bf16x4*)(wt + (size_t)c * EMB + d0) = o;
        if (threadIdx.x == 0) bsc[c] = bias[cc] * s;
    } else {
        const int col = (blockIdx.x - 96) * 16 + (threadIdx.x >> 3);
        const int d0  = (threadIdx.x & 7) * 4;
        bf16x4 o = { (__bf16)Wp[(size_t)(d0 + 0) * EMB + col],
                     (__bf16)Wp[(size_t)(d0 + 1) * EMB + col],
                     (__bf16)Wp[(size_t)(d0 + 2) * EMB + col],
                     (__bf16)Wp[(size_t)(d0 + 3) * EMB + col] };
        *(bf16x4*)(wpt + (size_t)col * HS + d0) = o;
    }
}

// ---------------------------------------------------------------------------
// Kernel 1: MFMA QKV projection, split-K x4.  (unchanged from R4/R6)
// ---------------------------------------------------------------------------
__global__ __launch_bounds__(256) void qkv_mfma(
    const float* __restrict__ x,
    const __bf16* __restrict__ wt, const float* __restrict__ bsc,
    __bf16* __restrict__ qbf, __bf16* __restrict__ kbf, __bf16* __restrict__ vtb)
{
    const int tid  = threadIdx.x;
    const int lane = tid & 63;
    const int w    = tid >> 6;
    const int lr = lane & 15;
    const int lh = lane >> 4;
    const int tok0 = blockIdx.x * 16;
    const int k0   = w * 128;

    const float*  xp = x + (size_t)(tok0 + lr) * EMB + k0 + lh * 8;
    const __bf16* wp = wt + (size_t)lr * EMB + k0 + lh * 8;

    const f32x4 z = {0.f, 0.f, 0.f, 0.f};
    f32x4 acc[6] = {z, z, z, z, z, z};

    bf16x8 xf_c, wf_c[6], xf_n, wf_n[6];
    {
        const float4 a4 = *(const float4*)(xp);
        const float4 b4 = *(const float4*)(xp + 4);
        xf_c = bf16x8{ (__bf16)a4.x, (__bf16)a4.y, (__bf16)a4.z, (__bf16)a4.w,
                       (__bf16)b4.x, (__bf16)b4.y, (__bf16)b4.z, (__bf16)b4.w };
        #pragma unroll
        for (int f = 0; f < 6; ++f)
            wf_c[f] = *(const bf16x8*)(wp + (size_t)f * 16 * EMB);
    }

    #pragma unroll
    for (int kt = 0; kt < 128; kt += 32) {
        const int ktn = (kt + 32 < 128) ? (kt + 32) : kt;
        {
            const float4 a4 = *(const float4*)(xp + ktn);
            const float4 b4 = *(const float4*)(xp + ktn + 4);
            xf_n = bf16x8{ (__bf16)a4.x, (__bf16)a4.y, (__bf16)a4.z, (__bf16)a4.w,
                           (__bf16)b4.x, (__bf16)b4.y, (__bf16)b4.z, (__bf16)b4.w };
            #pragma unroll
            for (int f = 0; f < 6; ++f)
                wf_n[f] = *(const bf16x8*)(wp + (size_t)f * 16 * EMB + ktn);
        }

        acc[0] = __builtin_amdgcn_mfma_f32_16x16x32_bf16(wf_c[0], xf_c, acc[0], 0, 0, 0);
        acc[1] = __builtin_amdgcn_mfma_f32_16x16x32_bf16(wf_c[1], xf_c, acc[1], 0, 0, 0);
        acc[2] = __builtin_amdgcn_mfma_f32_16x16x32_bf16(wf_c[2], xf_c, acc[2], 0, 0, 0);
        acc[3] = __builtin_amdgcn_mfma_f32_16x16x32_bf16(wf_c[3], xf_c, acc[3], 0, 0, 0);
        acc[4] = __builtin_amdgcn_mfma_f32_16x16x32_bf16(xf_c, wf_c[4], acc[4], 0, 0, 0);
        acc[5] = __builtin_amdgcn_mfma_f32_16x16x32_bf16(xf_c, wf_c[5], acc[5], 0, 0, 0);

        xf_c = xf_n;
        #pragma unroll
        for (int f = 0; f < 6; ++f) wf_c[f] = wf_n[f];
    }

    __shared__ float red[3 * 6 * 256];
    if (w > 0) {
        #pragma unroll
        for (int i = 0; i < 6; ++i)
            *(f32x4*)&red[((w - 1) * 6 + i) * 256 + lane * 4] = acc[i];
    }
    __syncthreads();
    if (w != 0) return;

    #pragma unroll
    for (int i = 0; i < 6; ++i)
        #pragma unroll
        for (int ww = 0; ww < 3; ++ww)
            acc[i] += *(const f32x4*)&red[(ww * 6 + i) * 256 + lane * 4];

    #pragma unroll
    for (int f = 0; f < 2; ++f) {
        const int cb = f * 16 + lh * 4;
        const float4 bqv = *(const float4*)(bsc + cb);
        const float4 bkv = *(const float4*)(bsc + 32 + cb);
        bf16x4 oq = { (__bf16)(acc[f][0] + bqv.x), (__bf16)(acc[f][1] + bqv.y),
                      (__bf16)(acc[f][2] + bqv.z), (__bf16)(acc[f][3] + bqv.w) };
        bf16x4 ok = { (__bf16)(acc[2+f][0] + bkv.x), (__bf16)(acc[2+f][1] + bkv.y),
                      (__bf16)(acc[2+f][2] + bkv.z), (__bf16)(acc[2+f][3] + bkv.w) };
        *(bf16x4*)(qbf + (size_t)(tok0 + lr) * HS + cb) = oq;
        *(bf16x4*)(kbf + (size_t)(tok0 + lr) * HS + cb) = ok;
    }
    {
        const int b    = tok0 >> 12;
        const int t_in = (tok0 & (TSEQ - 1)) + lh * 4;
        #pragma unroll
        for (int f = 0; f < 2; ++f) {
            const int d = f * 16 + lr;
            const float bv1 = bsc[64 + d];
            bf16x4 o = { (__bf16)(acc[4+f][0] + bv1), (__bf16)(acc[4+f][1] + bv1),
                         (__bf16)(acc[4+f][2] + bv1), (__bf16)(acc[4+f][3] + bv1) };
            *(bf16x4*)(vtb + ((size_t)(b * HS + d)) * TSEQ + t_in) = o;
        }
    }
}

// ---------------------------------------------------------------------------
// Kernel 2: FUSED attention + projection.  R6 STRUCTURE + R7 swapped-S path.
// grid(64 pairs, 4 batches), block 512 = 8 waves; block owns strips p and
// 127-p (129 balanced tiles); waves round-robin tiles.  Per tile: swapped
// QK^T (q lane-local) -> 4 packed ds_write_b64 -> 2 swizzled ds_read_b128
// A-frags -> x32 PV (pipelined S(t) || PV(t-1)).  lp = 2 per-lane scalars.
// Then LDS o-reduce, normalize, project vs bf16 Wp^T.  No running max.
// ---------------------------------------------------------------------------
__device__ __forceinline__ void s_stage2(
    const bf16x8 ck0, const bf16x8 ck1,
    const bf16x8 qb0, const bf16x8 qb1,
    int kt, int q0, int lr, int lh, int swz,
    float lp[2], char* Pb)
{
    const f32x4 z = {0.f, 0.f, 0.f, 0.f};
    // S^T[key][q]: A=K (row=key_l=lr, k=d), B=Q (col=q_l=lr, k=d)
    f32x4 st00 = __builtin_amdgcn_mfma_f32_16x16x32_bf16(ck0, qb0, z, 0, 0, 0);
    f32x4 st01 = __builtin_amdgcn_mfma_f32_16x16x32_bf16(ck1, qb0, z, 0, 0, 0);
    f32x4 st10 = __builtin_amdgcn_mfma_f32_16x16x32_bf16(ck0, qb1, z, 0, 0, 0);
    f32x4 st11 = __builtin_amdgcn_mfma_f32_16x16x32_bf16(ck1, qb1, z, 0, 0, 0);

    float P[2][2][4];   // [qh][kh][r]; key_l = kh*16+lh*4+r, q_l = qh*16+lr
    #pragma unroll
    for (int r = 0; r < 4; ++r) {
        P[0][0][r] = st00[r]; P[0][1][r] = st01[r];
        P[1][0][r] = st10[r]; P[1][1][r] = st11[r];
    }

    if (kt != q0) {                       // full tile (wave-uniform)
        #pragma unroll
        for (int qh = 0; qh < 2; ++qh)
            #pragma unroll
            for (int kh = 0; kh < 2; ++kh)
                #pragma unroll
                for (int r = 0; r < 4; ++r)
                    P[qh][kh][r] = __expf(P[qh][kh][r]);
    } else {                              // diagonal: key <= q mask
        #pragma unroll
        for (int qh = 0; qh < 2; ++qh)
            #pragma unroll
            for (int kh = 0; kh < 2; ++kh)
                #pragma unroll
                for (int r = 0; r < 4; ++r) {
                    const int key_l = kh * 16 + lh * 4 + r;
                    const int q_l   = qh * 16 + lr;
                    P[qh][kh][r] = (key_l <= q_l) ? __expf(P[qh][kh][r]) : 0.f;
                }
    }

    #pragma unroll
    for (int qh = 0; qh < 2; ++qh)
        #pragma unroll
        for (int kh = 0; kh < 2; ++kh)
            #pragma unroll
            for (int r = 0; r < 4; ++r)
                lp[qh] += P[qh][kh][r];

    // P^T[q][key] bf16, row stride 128B, 16B-chunk XOR swizzle by (q&7)
    #pragma unroll
    for (int qh = 0; qh < 2; ++qh)
        #pragma unroll
        for (int kh = 0; kh < 2; ++kh) {
            const int q    = qh * 16 + lr;
            const int byte = q * 128 + ((kh * 32 + lh * 8) ^ swz);
            bf16x4 pk = { (__bf16)P[qh][kh][0], (__bf16)P[qh][kh][1],
                          (__bf16)P[qh][kh][2], (__bf16)P[qh][kh][3] };
            *(bf16x4*)(Pb + byte) = pk;
        }
}

__device__ __forceinline__ void strip_proc2(
    int kt0, int kend, int q0,
    const bf16x8 qb0, const bf16x8 qb1,
    const __bf16* kbase, const __bf16* vbase,
    char* Pl,                         // 8KB: two 4KB buffers
    f32x4 o[4], float lp[2],
    int lr, int lh, int swz, int rdA, int rdB)
{
    if (kt0 >= kend) return;

    bf16x8 kf0 = *(const bf16x8*)(kbase + (size_t)kt0 * HS);
    bf16x8 kf1 = *(const bf16x8*)(kbase + (size_t)(kt0 + 16) * HS);
    bf16x8 vf0 = *(const bf16x8*)(vbase + kt0);
    bf16x8 vf1 = *(const bf16x8*)(vbase + kt0 + 16 * TSEQ);

    bf16x8 cv0p, cv1p;
    int pb = 1;
    {
        const bf16x8 ck0 = kf0, ck1 = kf1;
        cv0p = vf0; cv1p = vf1;
        const int ktn = (kt0 + 256 < kend) ? (kt0 + 256) : kt0;
        kf0 = *(const bf16x8*)(kbase + (size_t)ktn * HS);
        kf1 = *(const bf16x8*)(kbase + (size_t)(ktn + 16) * HS);
        vf0 = *(const bf16x8*)(vbase + ktn);
        vf1 = *(const bf16x8*)(vbase + ktn + 16 * TSEQ);
        s_stage2(ck0, ck1, qb0, qb1, kt0, q0, lr, lh, swz, lp, Pl);
    }

    for (int kt = kt0 + 256; kt < kend; kt += 256) {
        const bf16x8 ck0 = kf0, ck1 = kf1, cv0 = vf0, cv1 = vf1;
        const int ktn = (kt + 256 < kend) ? (kt + 256) : kt;
        kf0 = *(const bf16x8*)(kbase + (size_t)ktn * HS);
        kf1 = *(const bf16x8*)(kbase + (size_t)(ktn + 16) * HS);
        vf0 = *(const bf16x8*)(vbase + ktn);
        vf1 = *(const bf16x8*)(vbase + ktn + 16 * TSEQ);

        const char* pbase = Pl + (pb ^ 1) * 4096;
        const bf16x8 pa0 = *(const bf16x8*)(pbase + rdA);
        const bf16x8 pa1 = *(const bf16x8*)(pbase + rdB);

        s_stage2(ck0, ck1, qb0, qb1, kt, q0, lr, lh, swz, lp, Pl + pb * 4096);

        o[0] = __builtin_amdgcn_mfma_f32_16x16x32_bf16(pa0, cv0p, o[0], 0, 0, 0);
        o[1] = __builtin_amdgcn_mfma_f32_16x16x32_bf16(pa0, cv1p, o[1], 0, 0, 0);
        o[2] = __builtin_amdgcn_mfma_f32_16x16x32_bf16(pa1, cv0p, o[2], 0, 0, 0);
        o[3] = __builtin_amdgcn_mfma_f32_16x16x32_bf16(pa1, cv1p, o[3], 0, 0, 0);

        cv0p = cv0; cv1p = cv1; pb ^= 1;
    }

    {
        const char* pbase = Pl + (pb ^ 1) * 4096;
        const bf16x8 pa0 = *(const bf16x8*)(pbase + rdA);
        const bf16x8 pa1 = *(const bf16x8*)(pbase + rdB);
        o[0] = __builtin_amdgcn_mfma_f32_16x16x32_bf16(pa0, cv0p, o[0], 0, 0, 0);
        o[1] = __builtin_amdgcn_mfma_f32_16x16x32_bf16(pa0, cv1p, o[1], 0, 0, 0);
        o[2] = __builtin_amdgcn_mfma_f32_16x16x32_bf16(pa1, cv0p, o[2], 0, 0, 0);
        o[3] = __builtin_amdgcn_mfma_f32_16x16x32_bf16(pa1, cv1p, o[3], 0, 0, 0);
    }
}

__global__ __launch_bounds__(512) void attn_fused(
    const __bf16* __restrict__ qbf, const __bf16* __restrict__ kbf,
    const __bf16* __restrict__ vtb,
    const __bf16* __restrict__ wpt, const float* __restrict__ bp,
    float* __restrict__ out)
{
    const int p   = blockIdx.x;       // strips p and 127-p
    const int b   = blockIdx.y;
    const int tid = threadIdx.x;
    const int w    = tid >> 6;        // 0..7
    const int lane = tid & 63;
    const int lr = lane & 15;
    const int lh = lane >> 4;

    const int n0  = p + 1;            // tiles in strip0
    const int q00 = p * 32;
    const int q01 = (127 - p) * 32;

    // LDS: [0,64K) union{ Pl[8 waves][2][4096B] | red[8][2][4][256] f32 }
    //      [64K,66K) lpred[8][2][32] f32 ; [66K,70K) attn_s[2][32][32] bf16
    extern __shared__ char smem[];
    char*   myPl   = smem + w * 8192;
    float*  red    = (float*)smem;
    float*  lpred  = (float*)(smem + 65536);
    __bf16* attn_s = (__bf16*)(smem + 65536 + 2048);

    // Q B-frags (col=q_l=lr, k=d) for both strips
    const __bf16* qp0 = qbf + ((size_t)(b * TSEQ + q00 + lr)) * HS + lh * 8;
    const __bf16* qp1 = qbf + ((size_t)(b * TSEQ + q01 + lr)) * HS + lh * 8;
    const bf16x8 qb0s0 = *(const bf16x8*)qp0;
    const bf16x8 qb1s0 = *(const bf16x8*)(qp0 + 16 * HS);
    const bf16x8 qb0s1 = *(const bf16x8*)qp1;
    const bf16x8 qb1s1 = *(const bf16x8*)(qp1 + 16 * HS);

    const __bf16* kbase = kbf + ((size_t)(b * TSEQ + lr)) * HS + lh * 8;
    const __bf16* vbase = vtb + (size_t)(b * HS + lr) * TSEQ + lh * 8;

    const int swz = (lr & 7) << 4;
    const int rdA = lr * 128 + ((lh * 16) ^ swz);
    const int rdB = (16 + lr) * 128 + ((lh * 16) ^ swz);

    const f32x4 z = {0.f, 0.f, 0.f, 0.f};
    f32x4 o0[4] = {z, z, z, z};       // [qh*2+dh]
    f32x4 o1[4] = {z, z, z, z};
    float lp0[2] = {0.f, 0.f}, lp1[2] = {0.f, 0.f};

    // strip0 subset: tiles w, w+8, ... < n0
    strip_proc2(w * 32, q00 + 32, q00, qb0s0, qb1s0, kbase, vbase, myPl,
                o0, lp0, lr, lh, swz, rdA, rdB);
    // strip1 subset: rotated start for balance
    const int tb = n0 + ((w - n0) & 7);
    strip_proc2((tb - n0) * 32, q01 + 32, q01, qb0s1, qb1s1, kbase, vbase, myPl,
                o1, lp1, lr, lh, swz, rdA, rdB);

    // lp: lanes lh=0..3 share q=qh*16+lr -> xor 16, 32
    #pragma unroll
    for (int qh = 0; qh < 2; ++qh) {
        lp0[qh] += __shfl_xor(lp0[qh], 16, 64);
        lp0[qh] += __shfl_xor(lp0[qh], 32, 64);
        lp1[qh] += __shfl_xor(lp1[qh], 16, 64);
        lp1[qh] += __shfl_xor(lp1[qh], 32, 64);
    }

    __syncthreads();   // all PV reads of Pl done before red overwrites it

    #pragma unroll
    for (int f = 0; f < 4; ++f) {
        *(f32x4*)&red[((w * 2 + 0) * 4 + f) * 256 + lane * 4] = o0[f];
        *(f32x4*)&red[((w * 2 + 1) * 4 + f) * 256 + lane * 4] = o1[f];
    }
    if (lh == 0) {
        #pragma unroll
        for (int qh = 0; qh < 2; ++qh) {
            lpred[(w * 2 + 0) * 32 + qh * 16 + lr] = lp0[qh];
            lpred[(w * 2 + 1) * 32 + qh * 16 + lr] = lp1[qh];
        }
    }
    __syncthreads();

    // sum phase: wave w -> strip s = w>>2, fragment f = w&3 (qh=f>>1, dh=f&1)
    {
        const int s  = w >> 2;
        const int f  = w & 3;
        const int qh = f >> 1;
        const int dh = f & 1;
        f32x4 sum = z;
        #pragma unroll
        for (int ww = 0; ww < 8; ++ww)
            sum += *(const f32x4*)&red[((ww * 2 + s) * 4 + f) * 256 + lane * 4];

        #pragma unroll
        for (int r = 0; r < 4; ++r) {
            const int q = qh * 16 + lh * 4 + r;
            float L = 0.f;
            #pragma unroll
            for (int ww = 0; ww < 8; ++ww)
                L += lpred[(ww * 2 + s) * 32 + q];
            attn_s[(s * 32 + q) * 32 + dh * 16 + lr] = (__bf16)(sum[r] / L);
        }
    }
    __syncthreads();

    // projection: wave w -> strip sp = w>>2, cols [(w&3)*128, +128)
    {
        const int sp = w >> 2;
        const int c0 = (w & 3) * 128;
        const int qb0i = (sp == 0) ? q00 : q01;
        const __bf16* as = attn_s + sp * 1024;
        const bf16x8 a0 = *(const bf16x8*)(as + lr * 32 + lh * 8);
        const bf16x8 a1 = *(const bf16x8*)(as + (16 + lr) * 32 + lh * 8);

        #pragma unroll
        for (int g = 0; g < 8; ++g) {
            const int c = c0 + g * 16;
            const bf16x8 wb = *(const bf16x8*)(wpt + (size_t)(c + lr) * HS + lh * 8);
            f32x4 d0 = __builtin_amdgcn_mfma_f32_16x16x32_bf16(a0, wb, z, 0, 0, 0);
            f32x4 d1 = __builtin_amdgcn_mfma_f32_16x16x32_bf16(a1, wb, z, 0, 0, 0);
            const float bpv = bp[c + lr];
            #pragma unroll
            for (int r = 0; r < 4; ++r) {
                const int row = lh * 4 + r;
                out[(size_t)(b * TSEQ + qb0i + row)      * EMB + c + lr] = d0[r] + bpv;
                out[(size_t)(b * TSEQ + qb0i + 16 + row) * EMB + c + lr] = d1[r] + bpv;
            }
        }
    }
}

// ---------------------------------------------------------------------------
extern "C" void kernel_launch(void* const* d_in, const int* in_sizes, int n_in,
                              void* d_out, int out_size, void* d_ws, size_t ws_size,
                              hipStream_t stream)
{
    const float* x  = (const float*)d_in[0];
    const float* Wq = (const float*)d_in[1];
    const float* bq = (const float*)d_in[2];
    const float* Wk = (const float*)d_in[3];
    const float* bk = (const float*)d_in[4];
    const float* Wv = (const float*)d_in[5];
    const float* bv = (const float*)d_in[6];
    const float* Wp = (const float*)d_in[7];
    const float* bp = (const float*)d_in[8];
    float* out = (float*)d_out;

    char* ws = (char*)d_ws;
    __bf16* wt  = (__bf16*)(ws);
    float*  bsc = (float*)(ws + 96 * 1024);
    __bf16* wpt = (__bf16*)(ws + 128 * 1024);
    __bf16* qbf = (__bf16*)(ws + (size_t)1 * 1024 * 1024);
    __bf16* kbf = (__bf16*)(ws + (size_t)2 * 1024 * 1024);
    __bf16* vtb = (__bf16*)(ws + (size_t)3 * 1024 * 1024);

    wt_pack<<<dim3(128), 128, 0, stream>>>(Wq, bq, Wk, bk, Wv, bv, Wp,
                                           wt, bsc, wpt);
    qkv_mfma<<<dim3(NQ / 16), 256, 0, stream>>>(x, wt, bsc, qbf, kbf, vtb);
    attn_fused<<<dim3(64, NB), 512, 71680, stream>>>(qbf, kbf, vtb, wpt, bp, out);
}